// Round 1
// baseline (37195.755 us; speedup 1.0000x reference)
//
#include <hip/hip_runtime.h>
#include <hip/hip_bf16.h>

#define Bsz 64
#define Ssz 128
#define Hsz 1024
#define Vsz 50257
#define Tsz 32
#define NCHUNK 13   // ceil(V/4096)

__device__ __forceinline__ float sigmoidf_(float x) { return 1.0f / (1.0f + expf(-x)); }

// lengths[b] = count of nonzero input_ids in row b
__global__ __launch_bounds__(64) void k_lengths(const int* __restrict__ ids, int* __restrict__ lens)
{
    int b = threadIdx.x;
    int c = 0;
    for (int s = 0; s < Ssz; ++s) c += (ids[b * Ssz + s] != 0) ? 1 : 0;
    lens[b] = c;
}

// One LSTM step, fused: emb gather + x@Wih^T + h@Whh^T + bias + activations + masked state update.
// grid = H/2 blocks (2 features per block), block = 256 = 4 waves.
// wave w: msel = w&1 selects matrix (0: x/Wih, 1: h/Whh), khalf = w>>1 selects K-half.
// lane = batch. Weights fetched via wave-uniform s_load_dwordx4; x/h rows via per-lane float4.
__global__ __launch_bounds__(256) void k_lstm(
    const float* __restrict__ emb,
    const int* __restrict__ toks, int toff, int tstr,
    const float* __restrict__ hin, float* __restrict__ hout, float* __restrict__ cbuf,
    const float* __restrict__ Wih, const float* __restrict__ Whh,
    const float* __restrict__ bih, const float* __restrict__ bhh,
    const int* __restrict__ lens, int t, int masked)
{
    __shared__ float part[4][8][64];
    int tid = threadIdx.x;
    int b = tid & 63;
    int w = __builtin_amdgcn_readfirstlane(tid >> 6);
    int msel = w & 1;
    int khalf = w >> 1;
    int f0 = blockIdx.x * 2;

    const float* __restrict__ Wm = msel ? Whh : Wih;
    const float* src;
    if (msel == 0) {
        int id = toks[b * tstr + toff];
        src = emb + (size_t)id * Hsz;
    } else {
        src = hin + (size_t)b * Hsz;
    }

    float acc[8];
#pragma unroll
    for (int a = 0; a < 8; ++a) acc[a] = 0.f;

    const int k0 = khalf * 512;
    for (int k = k0; k < k0 + 512; k += 4) {
        float4 x = *(const float4*)(src + k);
#pragma unroll
        for (int g = 0; g < 4; ++g) {
            float4 w0 = *(const float4*)(Wm + (size_t)(g * Hsz + f0) * Hsz + k);
            float4 w1 = *(const float4*)(Wm + (size_t)(g * Hsz + f0 + 1) * Hsz + k);
            acc[g]     += x.x * w0.x + x.y * w0.y + x.z * w0.z + x.w * w0.w;
            acc[4 + g] += x.x * w1.x + x.y * w1.y + x.z * w1.z + x.w * w1.w;
        }
    }

#pragma unroll
    for (int a = 0; a < 8; ++a) part[w][a][b] = acc[a];
    __syncthreads();

    if (w < 2) {
        int fg = f0 + w;  // this wave finalizes feature fg
        float g4[4];
#pragma unroll
        for (int g = 0; g < 4; ++g)
            g4[g] = part[0][w * 4 + g][b] + part[1][w * 4 + g][b]
                  + part[2][w * 4 + g][b] + part[3][w * 4 + g][b]
                  + bih[g * Hsz + fg] + bhh[g * Hsz + fg];
        float gi = sigmoidf_(g4[0]);
        float gf = sigmoidf_(g4[1]);
        float gg = tanhf(g4[2]);
        float go = sigmoidf_(g4[3]);
        float cold = cbuf[fg * 64 + b];
        float cnew = gf * cold + gi * gg;
        float hnew = go * tanhf(cnew);
        if (masked) {
            if (!(t < lens[b])) { cnew = cold; hnew = hin[(size_t)b * Hsz + fg]; }
        }
        cbuf[fg * 64 + b] = cnew;
        hout[(size_t)b * Hsz + fg] = hnew;
    }
}

// logits[b][j] = h[b] . Wfc[j] + bfc[j], written straight to out[b][t][j].
// block = 256 = 4 waves; wave = 16 columns, lane = batch. grid = ceil(V/64).
__global__ __launch_bounds__(256) void k_logits(
    const float* __restrict__ h, const float* __restrict__ Wfc,
    const float* __restrict__ bfc, float* __restrict__ out, int t)
{
    int tid = threadIdx.x;
    int b = tid & 63;
    int w = __builtin_amdgcn_readfirstlane(tid >> 6);
    int j0 = blockIdx.x * 64 + w * 16;
    const float* __restrict__ hrow = h + (size_t)b * Hsz;

    const float* wr[16];
#pragma unroll
    for (int c2 = 0; c2 < 16; ++c2) {
        int j = j0 + c2;
        if (j > Vsz - 1) j = Vsz - 1;  // clamp row (stores are guarded)
        wr[c2] = Wfc + (size_t)j * Hsz;
    }
    float acc[16];
#pragma unroll
    for (int c2 = 0; c2 < 16; ++c2) acc[c2] = 0.f;

    for (int k = 0; k < Hsz; k += 4) {
        float4 x = *(const float4*)(hrow + k);
#pragma unroll
        for (int c2 = 0; c2 < 16; ++c2) {
            float4 wv = *(const float4*)(wr[c2] + k);
            acc[c2] += x.x * wv.x + x.y * wv.y + x.z * wv.z + x.w * wv.w;
        }
    }

    size_t ob = ((size_t)b * Tsz + t) * Vsz;
#pragma unroll
    for (int c2 = 0; c2 < 16; ++c2) {
        int j = j0 + c2;
        if (j < Vsz) out[ob + j] = acc[c2] + bfc[j];
    }
}

// Per-(chunk, batch) partial argmax over j, exact first-index tie semantics.
__global__ __launch_bounds__(256) void k_argmax_part(
    const float* __restrict__ out, int t, float* __restrict__ candV, int* __restrict__ candJ)
{
    int c = blockIdx.x, b = blockIdx.y, tid = threadIdx.x;
    const float* row = out + ((size_t)b * Tsz + t) * Vsz;
    float best = -INFINITY;
    int bj = 0;
    int base = c * 4096;
    for (int i = 0; i < 16; ++i) {
        int j = base + i * 256 + tid;   // ascending j per thread; strict > keeps first max
        if (j < Vsz) {
            float v = row[j];
            if (v > best) { best = v; bj = j; }
        }
    }
    __shared__ float sv[256];
    __shared__ int sj[256];
    sv[tid] = best; sj[tid] = bj;
    __syncthreads();
    for (int s = 128; s > 0; s >>= 1) {
        if (tid < s) {
            float ov = sv[tid + s]; int oj = sj[tid + s];
            if (ov > sv[tid] || (ov == sv[tid] && oj < sj[tid])) { sv[tid] = ov; sj[tid] = oj; }
        }
        __syncthreads();
    }
    if (tid == 0) { candV[b * NCHUNK + c] = sv[0]; candJ[b * NCHUNK + c] = sj[0]; }
}

__global__ __launch_bounds__(64) void k_argmax_comb(
    const float* __restrict__ candV, const int* __restrict__ candJ, int* __restrict__ tok)
{
    int b = threadIdx.x;
    float best = -INFINITY;
    int bj = 0x7fffffff;
    for (int c = 0; c < NCHUNK; ++c) {
        float v = candV[b * NCHUNK + c];
        int j = candJ[b * NCHUNK + c];
        if (v > best || (v == best && j < bj)) { best = v; bj = j; }
    }
    tok[b] = bj;
}

extern "C" void kernel_launch(void* const* d_in, const int* in_sizes, int n_in,
                              void* d_out, int out_size, void* d_ws, size_t ws_size,
                              hipStream_t stream)
{
    const int*   ids = (const int*)d_in[0];
    // d_in[1] = max_new_tokens (always 32; grid shapes are static for capture)
    const float* emb = (const float*)d_in[2];
    const float* Wih = (const float*)d_in[3];
    const float* Whh = (const float*)d_in[4];
    const float* bih = (const float*)d_in[5];
    const float* bhh = (const float*)d_in[6];
    const float* Wfc = (const float*)d_in[7];
    const float* bfc = (const float*)d_in[8];
    float* out = (float*)d_out;

    char* p = (char*)d_ws;
    float* hA    = (float*)p; p += (size_t)Bsz * Hsz * sizeof(float);  // h row-major [b][k]
    float* hB    = (float*)p; p += (size_t)Bsz * Hsz * sizeof(float);
    float* cb    = (float*)p; p += (size_t)Hsz * Bsz * sizeof(float);  // c [feature][b]
    float* candV = (float*)p; p += (size_t)Bsz * NCHUNK * sizeof(float);
    int*   candJ = (int*)p;   p += (size_t)Bsz * NCHUNK * sizeof(int);
    int*   lens  = (int*)p;   p += (size_t)Bsz * sizeof(int);
    int*   tok   = (int*)p;   p += (size_t)Bsz * sizeof(int);

    (void)hipMemsetAsync(hA, 0, (size_t)Bsz * Hsz * sizeof(float), stream);
    (void)hipMemsetAsync(cb, 0, (size_t)Hsz * Bsz * sizeof(float), stream);
    k_lengths<<<1, 64, 0, stream>>>(ids, lens);

    float* cur = hA;
    float* nxt = hB;

    // Prompt: 128 masked steps (x = emb[input_ids[:, t]])
    for (int t = 0; t < Ssz; ++t) {
        k_lstm<<<Hsz / 2, 256, 0, stream>>>(emb, ids, t, Ssz, cur, nxt, cb,
                                            Wih, Whh, bih, bhh, lens, t, 1);
        float* tmp = cur; cur = nxt; nxt = tmp;
    }
    k_logits<<<(Vsz + 63) / 64, 256, 0, stream>>>(cur, Wfc, bfc, out, 0);

    // Decode: 31 steps with argmax feedback
    for (int t = 1; t < Tsz; ++t) {
        k_argmax_part<<<dim3(NCHUNK, Bsz), 256, 0, stream>>>(out, t - 1, candV, candJ);
        k_argmax_comb<<<1, 64, 0, stream>>>(candV, candJ, tok);
        k_lstm<<<Hsz / 2, 256, 0, stream>>>(emb, tok, 0, 1, cur, nxt, cb,
                                            Wih, Whh, bih, bhh, nullptr, 0, 0);
        float* tmp = cur; cur = nxt; nxt = tmp;
        k_logits<<<(Vsz + 63) / 64, 256, 0, stream>>>(cur, Wfc, bfc, out, t);
    }
}